// Round 7
// baseline (164.604 us; speedup 1.0000x reference)
//
#include <hip/hip_runtime.h>
#include <hip/hip_fp16.h>

// HartleyConv2d: out[b,o,u,v] = (0.5/132^2) * sum_c [ X*(W+Wf) + Xf*(W-Wf) ]
// X = DHT2(pad1(x) zero-padded to 132); both DHT passes share the same
// phase-shifted cas table T[r][k] = cas(2pi r (k+1) / 132)  (spatial pad folds in).
// ALL I/O fp32: x [8,64,128,128], w [64,64,3,3], out [8,64,128,128].
// dht2_fused: block = (b,c) plane x one of 3 v-chunks (48 rows); Y1 chunk in LDS.

#define SCALE (0.5f / 17424.0f)

typedef __attribute__((ext_vector_type(8))) _Float16 f16x8;
typedef __attribute__((ext_vector_type(4))) _Float16 f16x4;
typedef __attribute__((ext_vector_type(4))) float    f32x4;

// ---------------------------------------------------------------- table ----
// Tf [144][128] f16: rows 132..143 are zero padding (for 16-row m/n tiles).
__global__ void build_tf16(_Float16* __restrict__ Tf) {
    const int u = blockIdx.x;    // 0..143
    const int i = threadIdx.x;   // 0..127
    float val = 0.f;
    if (u < 132) {
        const int m = (u * (i + 1)) % 132;
        const float step = 6.28318530717958647692f / 132.0f;
        float s, c;
        sincosf((float)m * step, &s, &c);
        val = c + s;
    }
    Tf[u * 128 + i] = (_Float16)val;
}

// ------------------------------------------------------------ build_hgT ----
// hgT[u][kt][o][c], kt=0..2 -> h_j, kt=3..5 -> g_j   (f16)
__global__ __launch_bounds__(256) void build_hgT(
    const float* __restrict__ w, __half* __restrict__ hgT)
{
    const int u = blockIdx.x;   // 0..127
    const float step = 6.28318530717958647692f / 132.0f;
    float a[3], ap[3];
    a[0] = 1.f; ap[0] = 1.f;
    #pragma unroll
    for (int i = 1; i < 3; ++i) {
        float s, c;
        sincosf((float)((u * i) % 132) * step, &s, &c);
        a[i] = c + s;                                   // cas(2pi*u*i/132)
        sincosf((float)(((u + 1) * i) % 132) * step, &s, &c);
        ap[i] = c - s;                                  // cas(-2pi*(u+1)*i/132)
    }
    for (int it = 0; it < 16; ++it) {
        const int oc = it * 256 + threadIdx.x;          // o*64+c
        const float* wp = w + (size_t)oc * 9;
        float w9[9];
        #pragma unroll
        for (int q = 0; q < 9; ++q) w9[q] = wp[q];
        #pragma unroll
        for (int j = 0; j < 3; ++j) {
            const float h = a[0]*w9[j] + a[1]*w9[3+j] + a[2]*w9[6+j];
            const float g = ap[0]*w9[j] + ap[1]*w9[3+j] + ap[2]*w9[6+j];
            hgT[((size_t)u * 6 + j)     * 4096 + oc] = __float2half(h);
            hgT[((size_t)u * 6 + 3 + j) * 4096 + oc] = __float2half(g);
        }
    }
}

// ------------------------------------------------------------ dht2_fused ----
// grid(512, 3): block = (b,c) plane, v rows [vs*48, vs*48+48). 256 thr (4 waves).
// pass A: Y1l[vloc][i] = sum_j Tf[vs*48+vloc][j] * x[i][j]
// pass B: X[u][vg]     = sum_i Tf[u][i] * Y1l[vloc][i]
__global__ __launch_bounds__(256) void dht2_fused(
    const float* __restrict__ x, const _Float16* __restrict__ Tf,
    _Float16* __restrict__ X)
{
    const int bc = blockIdx.x;
    const int vs = blockIdx.y;                    // 0..2
    const int tid = threadIdx.x, wv = tid >> 6, lane = tid & 63;
    const int col = lane & 15, quad = lane >> 4;
    __shared__ _Float16 Y1l[48][136];             // [vloc][i], stride 136

    const float* xp = x + (size_t)bc * 16384;

    // ---- pass A: wave wv covers i-tiles {2wv, 2wv+1}, local v-tiles 0..2
    #pragma unroll
    for (int nt = 0; nt < 2; ++nt) {
        const int ic = (wv * 2 + nt) * 16 + col;  // i of B-frag / D col
        f32x4 acc[3];
        #pragma unroll
        for (int mt = 0; mt < 3; ++mt) acc[mt] = (f32x4)0.f;
        #pragma unroll
        for (int kc = 0; kc < 4; ++kc) {
            const int k0 = kc * 32 + quad * 8;
            const float4 xa = *(const float4*)(xp + (size_t)ic * 128 + k0);
            const float4 xb = *(const float4*)(xp + (size_t)ic * 128 + k0 + 4);
            f16x8 bf;
            bf[0] = (_Float16)xa.x; bf[1] = (_Float16)xa.y;
            bf[2] = (_Float16)xa.z; bf[3] = (_Float16)xa.w;
            bf[4] = (_Float16)xb.x; bf[5] = (_Float16)xb.y;
            bf[6] = (_Float16)xb.z; bf[7] = (_Float16)xb.w;
            #pragma unroll
            for (int mt = 0; mt < 3; ++mt) {
                const f16x8 af = *(const f16x8*)(
                    Tf + (size_t)(vs * 48 + mt * 16 + col) * 128 + k0);
                acc[mt] = __builtin_amdgcn_mfma_f32_16x16x32_f16(af, bf, acc[mt], 0, 0, 0);
            }
        }
        #pragma unroll
        for (int mt = 0; mt < 3; ++mt)
            #pragma unroll
            for (int r = 0; r < 4; ++r)
                Y1l[mt * 16 + quad * 4 + r][ic] = (_Float16)acc[mt][r];
    }
    __syncthreads();

    // ---- pass B: 27 (mt,nt) pairs round-robined over 4 waves
    _Float16* Xp = X + (size_t)bc * 17424;
    for (int t = 0; t < 7; ++t) {
        const int p = wv + 4 * t;
        if (p < 27) {
            const int mt = p % 9, nt = p / 9;     // u-tile, local v-tile
            const int vloc = nt * 16 + col;       // B-frag col
            f32x4 acc = (f32x4)0.f;
            #pragma unroll
            for (int kc = 0; kc < 4; ++kc) {
                const int k0 = kc * 32 + quad * 8;
                const f16x8 bf = *(const f16x8*)&Y1l[vloc][k0];
                const f16x8 af = *(const f16x8*)(
                    Tf + (size_t)(mt * 16 + col) * 128 + k0);
                acc = __builtin_amdgcn_mfma_f32_16x16x32_f16(af, bf, acc, 0, 0, 0);
            }
            const int vg = vs * 48 + vloc;
            if (vg < 132) {
                #pragma unroll
                for (int r = 0; r < 4; ++r) {
                    const int u = mt * 16 + quad * 4 + r;
                    if (u < 132) Xp[u * 132 + vg] = (_Float16)acc[r];
                }
            }
        }
    }
}

// ---------------------------------------------------------- combine MFMA ----
// grid (128 u, 8 b), 256 threads (4 waves). Per block: M=64(o), N=128(v), K=384.
__global__ __launch_bounds__(256) void combine_mfma(
    const __half* __restrict__ Xh, const __half* __restrict__ hgTh,
    float* __restrict__ out)
{
    const int u = blockIdx.x;       // 0..127
    const int b = blockIdx.y;       // 0..7
    const int tid = threadIdx.x;
    const int wv = tid >> 6, lane = tid & 63;
    const int col = lane & 15, quad = lane >> 4;

    __shared__ _Float16 Ps[128][72];   // [v][c], stride 72 (bank-safe)
    __shared__ _Float16 Ms[128][72];

    const _Float16* X = (const _Float16*)Xh;

    // ---- stage P/M: thread -> c = tid>>2, vq = (tid&3)*32, 8 quads of 4 v
    {
        const int c  = tid >> 2;
        const int vq = (tid & 3) * 32;
        const _Float16* rowd = X + (size_t)(b * 64 + c) * 17424 + (size_t)u * 132;
        const _Float16* rowm = X + (size_t)(b * 64 + c) * 17424 + (size_t)(131 - u) * 132;
        #pragma unroll
        for (int k = 0; k < 8; ++k) {
            const int v0 = vq + 4 * k;
            const f16x4 d = *(const f16x4*)(rowd + v0);          // X(u, v0..v0+3)
            const f16x4 m = *(const f16x4*)(rowm + (128 - v0));  // X(131-u, 128-v0..131-v0)
            #pragma unroll
            for (int i = 0; i < 4; ++i) {
                Ps[v0 + i][c] = d[i] + m[3 - i];
                Ms[v0 + i][c] = d[i] - m[3 - i];
            }
        }
    }

    // ---- per-lane coefficients: cf[nt][kt] for v = wv*32 + nt*16 + col
    const float step = 6.28318530717958647692f / 132.0f;
    _Float16 cf[2][6];
    #pragma unroll
    for (int nt = 0; nt < 2; ++nt) {
        const int v = wv * 32 + nt * 16 + col;
        cf[nt][0] = (_Float16)1.0f;
        cf[nt][3] = (_Float16)1.0f;
        #pragma unroll
        for (int j = 1; j < 3; ++j) {
            float s, c;
            sincosf((float)((v * j) % 132) * step, &s, &c);
            cf[nt][j] = (_Float16)(c + s);                 // bv_j(v)
            sincosf((float)(((v + 1) * j) % 132) * step, &s, &c);
            cf[nt][3 + j] = (_Float16)(c - s);             // bp_j(v)
        }
    }
    __syncthreads();

    // ---- MFMA main loop: 12 K-chunks of 32 (kt = chunk>>1, c0 = (chunk&1)*32)
    const _Float16* hgu = (const _Float16*)hgTh + (size_t)u * 6 * 4096;
    f32x4 acc[4][2];
    #pragma unroll
    for (int mt = 0; mt < 4; ++mt)
        #pragma unroll
        for (int nt = 0; nt < 2; ++nt)
            acc[mt][nt] = (f32x4)0.0f;

    #pragma unroll
    for (int ch = 0; ch < 12; ++ch) {
        const int kt = ch >> 1, c0 = (ch & 1) * 32;
        f16x8 af[4];
        #pragma unroll
        for (int mt = 0; mt < 4; ++mt) {
            const int o = mt * 16 + col;
            af[mt] = *(const f16x8*)(hgu + ((size_t)kt * 64 + o) * 64 + c0 + quad * 8);
        }
        #pragma unroll
        for (int nt = 0; nt < 2; ++nt) {
            const int v = wv * 32 + nt * 16 + col;
            f16x8 bf = (kt < 3)
                ? *(const f16x8*)&Ps[v][c0 + quad * 8]
                : *(const f16x8*)&Ms[v][c0 + quad * 8];
            const _Float16 cs = cf[nt][kt];
            #pragma unroll
            for (int e = 0; e < 8; ++e) bf[e] *= cs;
            #pragma unroll
            for (int mt = 0; mt < 4; ++mt)
                acc[mt][nt] = __builtin_amdgcn_mfma_f32_16x16x32_f16(
                    af[mt], bf, acc[mt][nt], 0, 0, 0);
        }
    }

    // ---- epilogue: C-layout -> out[b][o][u][v], coalesced 64B in v
    #pragma unroll
    for (int mt = 0; mt < 4; ++mt) {
        #pragma unroll
        for (int nt = 0; nt < 2; ++nt) {
            const int v = wv * 32 + nt * 16 + col;
            #pragma unroll
            for (int r = 0; r < 4; ++r) {
                const int o = mt * 16 + quad * 4 + r;
                out[(((size_t)b * 64 + o) * 128 + u) * 128 + v] = acc[mt][nt][r] * SCALE;
            }
        }
    }
}

// ----------------------------------------------------------------- launch ----
extern "C" void kernel_launch(void* const* d_in, const int* in_sizes, int n_in,
                              void* d_out, int out_size, void* d_ws, size_t ws_size,
                              hipStream_t stream)
{
    const float* x = (const float*)d_in[0];   // fp32 [8,64,128,128]
    const float* w = (const float*)d_in[1];   // fp32 [64,64,3,3]
    char* ws = (char*)d_ws;
    // byte layout:
    //   Tf  f16 @ 0          (36,864 B)     [144][128]
    //   X   f16 @ 65,536     (17,842,176 B) [512 x 132 x 132]
    //   hgT f16 @ 17,907,712 (6,291,456 B)  [128][6][64][64]
    // total ~24.2 MB
    _Float16* Tf  = (_Float16*)(ws);
    _Float16* X   = (_Float16*)(ws + 65536);
    __half*   hgT = (__half*)(ws + 17907712);

    build_tf16<<<dim3(144), dim3(128), 0, stream>>>(Tf);

    // fused DHT2: x -> X (Y1 chunks live in LDS; 3 v-chunks per plane)
    dht2_fused<<<dim3(512, 3), dim3(256), 0, stream>>>(x, Tf, X);

    // per-u weight transform
    build_hgT<<<dim3(128), dim3(256), 0, stream>>>(w, hgT);

    // combine as MFMA GEMM -> fp32 out
    combine_mfma<<<dim3(128, 8), dim3(256), 0, stream>>>(
        (const __half*)X, hgT, (float*)d_out);
}

// Round 8
// 119.216 us; speedup vs baseline: 1.3807x; 1.3807x over previous
//
#include <hip/hip_runtime.h>
#include <hip/hip_fp16.h>

// HartleyConv2d: out[b,o,u,v] = (0.5/132^2) * sum_c [ X*(W+Wf) + Xf*(W-Wf) ]
// X = DHT2(pad1(x) zero-padded to 132); DHT table T[r][k] = cas(2pi r (k+1)/132).
// ALL I/O fp32: x [8,64,128,128], w [64,64,3,3], out [8,64,128,128].
// R8: all MFMA operands staged in LDS (Tf > L1 was causing per-MFMA L2 trips).

#define SCALE (0.5f / 17424.0f)

typedef __attribute__((ext_vector_type(8))) _Float16 f16x8;
typedef __attribute__((ext_vector_type(4))) _Float16 f16x4;
typedef __attribute__((ext_vector_type(4))) float    f32x4;

// ---------------------------------------------------------------- table ----
// Tf [144][128] f16: rows 132..143 zero (pad for 16-row tiles).
__global__ void build_tf16(_Float16* __restrict__ Tf) {
    const int u = blockIdx.x;    // 0..143
    const int i = threadIdx.x;   // 0..127
    float val = 0.f;
    if (u < 132) {
        const int m = (u * (i + 1)) % 132;
        const float step = 6.28318530717958647692f / 132.0f;
        float s, c;
        sincosf((float)m * step, &s, &c);
        val = c + s;
    }
    Tf[u * 128 + i] = (_Float16)val;
}

// cfT[v][8]: {1, bv1, bv2, 1, bp1, bp2, 0, 0} f16, v = 0..127
__global__ void build_cf(_Float16* __restrict__ cfT) {
    const int v = threadIdx.x;   // 0..127
    const float step = 6.28318530717958647692f / 132.0f;
    float s, c;
    _Float16 o[8];
    o[0] = (_Float16)1.0f; o[3] = (_Float16)1.0f;
    o[6] = (_Float16)0.0f; o[7] = (_Float16)0.0f;
    sincosf((float)((v * 1) % 132) * step, &s, &c);      o[1] = (_Float16)(c + s);
    sincosf((float)((v * 2) % 132) * step, &s, &c);      o[2] = (_Float16)(c + s);
    sincosf((float)(((v + 1) * 1) % 132) * step, &s, &c); o[4] = (_Float16)(c - s);
    sincosf((float)(((v + 1) * 2) % 132) * step, &s, &c); o[5] = (_Float16)(c - s);
    *(f16x8*)(cfT + v * 8) = *(f16x8*)o;
}

// ------------------------------------------------------------ build_hgT ----
// hgT[u][kt][o][c], kt=0..2 -> h_j, kt=3..5 -> g_j   (f16)
__global__ __launch_bounds__(256) void build_hgT(
    const float* __restrict__ w, _Float16* __restrict__ hgT)
{
    const int u = blockIdx.x;   // 0..127
    const float step = 6.28318530717958647692f / 132.0f;
    float a[3], ap[3];
    a[0] = 1.f; ap[0] = 1.f;
    #pragma unroll
    for (int i = 1; i < 3; ++i) {
        float s, c;
        sincosf((float)((u * i) % 132) * step, &s, &c);
        a[i] = c + s;                                   // cas(2pi*u*i/132)
        sincosf((float)(((u + 1) * i) % 132) * step, &s, &c);
        ap[i] = c - s;                                  // cas(-2pi*(u+1)*i/132)
    }
    for (int it = 0; it < 16; ++it) {
        const int oc = it * 256 + threadIdx.x;          // o*64+c
        const float* wp = w + (size_t)oc * 9;
        float w9[9];
        #pragma unroll
        for (int q = 0; q < 9; ++q) w9[q] = wp[q];
        #pragma unroll
        for (int j = 0; j < 3; ++j) {
            const float h = a[0]*w9[j] + a[1]*w9[3+j] + a[2]*w9[6+j];
            const float g = ap[0]*w9[j] + ap[1]*w9[3+j] + ap[2]*w9[6+j];
            hgT[((size_t)u * 6 + j)     * 4096 + oc] = (_Float16)h;
            hgT[((size_t)u * 6 + 3 + j) * 4096 + oc] = (_Float16)g;
        }
    }
}

// ------------------------------------------------------------ dht2_fused ----
// grid(512): block = one (b,c) plane, 256 thr (4 waves). Tf staged in LDS.
// pass A: Y1l[v][i] = sum_j Tfl[v][j] * x[i][j]
// pass B: X[u][v]   = sum_i Tfl[u][i] * Y1l[v][i]
__global__ __launch_bounds__(256, 2) void dht2_fused(
    const float* __restrict__ x, const _Float16* __restrict__ Tf,
    _Float16* __restrict__ X)
{
    const int bc = blockIdx.x;
    const int tid = threadIdx.x, wv = tid >> 6, lane = tid & 63;
    const int col = lane & 15, quad = lane >> 4;
    __shared__ _Float16 Tfl[144][136];   // stride 136 (272 B): conflict-minimal
    __shared__ _Float16 Y1l[144][136];

    const float* xp = x + (size_t)bc * 16384;

    // ---- hoist ALL x loads for this wave's two i-tiles (issued up front)
    float4 xv[2][4][2];
    #pragma unroll
    for (int nt = 0; nt < 2; ++nt) {
        const int ic = (wv * 2 + nt) * 16 + col;
        #pragma unroll
        for (int kc = 0; kc < 4; ++kc) {
            const int k0 = kc * 32 + quad * 8;
            xv[nt][kc][0] = *(const float4*)(xp + ic * 128 + k0);
            xv[nt][kc][1] = *(const float4*)(xp + ic * 128 + k0 + 4);
        }
    }
    // ---- stage Tf -> Tfl (36,864 B in 16B chunks)
    #pragma unroll
    for (int s = 0; s < 9; ++s) {
        const int idx = tid + 256 * s;        // chunk id 0..2303
        const int row = idx >> 4;
        const int ce  = (idx & 15) * 8;
        *(f16x8*)&Tfl[row][ce] = *(const f16x8*)(Tf + (size_t)idx * 8);
    }
    // ---- convert x to f16 B-fragments
    f16x8 bfA[2][4];
    #pragma unroll
    for (int nt = 0; nt < 2; ++nt)
        #pragma unroll
        for (int kc = 0; kc < 4; ++kc) {
            f16x8 t;
            t[0] = (_Float16)xv[nt][kc][0].x; t[1] = (_Float16)xv[nt][kc][0].y;
            t[2] = (_Float16)xv[nt][kc][0].z; t[3] = (_Float16)xv[nt][kc][0].w;
            t[4] = (_Float16)xv[nt][kc][1].x; t[5] = (_Float16)xv[nt][kc][1].y;
            t[6] = (_Float16)xv[nt][kc][1].z; t[7] = (_Float16)xv[nt][kc][1].w;
            bfA[nt][kc] = t;
        }
    __syncthreads();

    // ---- pass A: dense MFMA, all operands LDS/regs
    f32x4 accA[2][9];
    #pragma unroll
    for (int nt = 0; nt < 2; ++nt)
        #pragma unroll
        for (int mt = 0; mt < 9; ++mt) accA[nt][mt] = (f32x4)0.f;
    #pragma unroll
    for (int kc = 0; kc < 4; ++kc) {
        const int k0 = kc * 32 + quad * 8;
        #pragma unroll
        for (int mt = 0; mt < 9; ++mt) {
            const f16x8 af = *(const f16x8*)&Tfl[mt * 16 + col][k0];
            accA[0][mt] = __builtin_amdgcn_mfma_f32_16x16x32_f16(af, bfA[0][kc], accA[0][mt], 0, 0, 0);
            accA[1][mt] = __builtin_amdgcn_mfma_f32_16x16x32_f16(af, bfA[1][kc], accA[1][mt], 0, 0, 0);
        }
    }
    #pragma unroll
    for (int nt = 0; nt < 2; ++nt) {
        const int ic = (wv * 2 + nt) * 16 + col;
        #pragma unroll
        for (int mt = 0; mt < 9; ++mt)
            #pragma unroll
            for (int r = 0; r < 4; ++r)
                Y1l[mt * 16 + quad * 4 + r][ic] = (_Float16)accA[nt][mt][r];
    }
    __syncthreads();

    // ---- pass B: wave wv covers v-tiles {wv, wv+4, wv+8}; af9 reused across nt
    f32x4 accB[3][9];
    #pragma unroll
    for (int t = 0; t < 3; ++t)
        #pragma unroll
        for (int mt = 0; mt < 9; ++mt) accB[t][mt] = (f32x4)0.f;
    #pragma unroll
    for (int kc = 0; kc < 4; ++kc) {
        const int k0 = kc * 32 + quad * 8;
        f16x8 af9[9];
        #pragma unroll
        for (int mt = 0; mt < 9; ++mt)
            af9[mt] = *(const f16x8*)&Tfl[mt * 16 + col][k0];
        #pragma unroll
        for (int t = 0; t < 3; ++t) {
            const int nt = wv + 4 * t;
            if (nt < 9) {
                const f16x8 bf = *(const f16x8*)&Y1l[nt * 16 + col][k0];
                #pragma unroll
                for (int mt = 0; mt < 9; ++mt)
                    accB[t][mt] = __builtin_amdgcn_mfma_f32_16x16x32_f16(af9[mt], bf, accB[t][mt], 0, 0, 0);
            }
        }
    }
    _Float16* Xp = X + (size_t)bc * 17424;
    #pragma unroll
    for (int t = 0; t < 3; ++t) {
        const int nt = wv + 4 * t;
        if (nt < 9) {
            const int vg = nt * 16 + col;
            if (vg < 132) {
                #pragma unroll
                for (int mt = 0; mt < 9; ++mt)
                    #pragma unroll
                    for (int r = 0; r < 4; ++r) {
                        const int u = mt * 16 + quad * 4 + r;
                        if (u < 132) Xp[u * 132 + vg] = (_Float16)accB[t][mt][r];
                    }
            }
        }
    }
}

// ---------------------------------------------------------- combine MFMA ----
// grid (128 u, 8 b), 256 thr (4 waves). Wave wv owns o-tile mt=wv; nt = 8 v-tiles.
// af (hgT) hoisted 6-at-a-time; bf from LDS; cf from tiny global table.
__global__ __launch_bounds__(256) void combine_mfma(
    const _Float16* __restrict__ X, const _Float16* __restrict__ hgT,
    const _Float16* __restrict__ cfT, float* __restrict__ out)
{
    const int u = blockIdx.x;       // 0..127
    const int b = blockIdx.y;       // 0..7
    const int tid = threadIdx.x;
    const int wv = tid >> 6, lane = tid & 63;
    const int col = lane & 15, quad = lane >> 4;

    __shared__ _Float16 Ps[128][72];   // [v][c], stride 72 (bank-safe)
    __shared__ _Float16 Ms[128][72];

    // ---- stage P/M
    {
        const int c  = tid >> 2;
        const int vq = (tid & 3) * 32;
        const _Float16* rowd = X + (size_t)(b * 64 + c) * 17424 + (size_t)u * 132;
        const _Float16* rowm = X + (size_t)(b * 64 + c) * 17424 + (size_t)(131 - u) * 132;
        #pragma unroll
        for (int k = 0; k < 8; ++k) {
            const int v0 = vq + 4 * k;
            const f16x4 d = *(const f16x4*)(rowd + v0);          // X(u, v0..v0+3)
            const f16x4 m = *(const f16x4*)(rowm + (128 - v0));  // X(131-u, ...)
            #pragma unroll
            for (int i = 0; i < 4; ++i) {
                Ps[v0 + i][c] = d[i] + m[3 - i];
                Ms[v0 + i][c] = d[i] - m[3 - i];
            }
        }
    }
    // ---- per-lane coefficients from table: cfv[nt][0..5]
    f16x8 cfv[8];
    #pragma unroll
    for (int nt = 0; nt < 8; ++nt)
        cfv[nt] = *(const f16x8*)(cfT + (size_t)(nt * 16 + col) * 8);
    __syncthreads();

    const _Float16* hgu = hgT + (size_t)u * 6 * 4096;
    const int orow = wv * 16 + col;
    f32x4 acc[8];
    #pragma unroll
    for (int nt = 0; nt < 8; ++nt) acc[nt] = (f32x4)0.f;

    // ---- P phase (kt 0..2), af hoisted
    {
        f16x8 af[6];
        #pragma unroll
        for (int ch = 0; ch < 6; ++ch) {
            const int kt = ch >> 1, c0 = (ch & 1) * 32;
            af[ch] = *(const f16x8*)(hgu + ((size_t)kt * 64 + orow) * 64 + c0 + quad * 8);
        }
        #pragma unroll
        for (int ch = 0; ch < 6; ++ch) {
            const int kt = ch >> 1, c0 = (ch & 1) * 32;
            #pragma unroll
            for (int nt = 0; nt < 8; ++nt) {
                f16x8 bf = *(const f16x8*)&Ps[nt * 16 + col][c0 + quad * 8];
                const _Float16 cs = cfv[nt][kt];
                #pragma unroll
                for (int e = 0; e < 8; ++e) bf[e] *= cs;
                acc[nt] = __builtin_amdgcn_mfma_f32_16x16x32_f16(af[ch], bf, acc[nt], 0, 0, 0);
            }
        }
    }
    // ---- M phase (kt 3..5)
    {
        f16x8 af[6];
        #pragma unroll
        for (int ch = 0; ch < 6; ++ch) {
            const int kt = 3 + (ch >> 1), c0 = (ch & 1) * 32;
            af[ch] = *(const f16x8*)(hgu + ((size_t)kt * 64 + orow) * 64 + c0 + quad * 8);
        }
        #pragma unroll
        for (int ch = 0; ch < 6; ++ch) {
            const int kt = 3 + (ch >> 1), c0 = (ch & 1) * 32;
            #pragma unroll
            for (int nt = 0; nt < 8; ++nt) {
                f16x8 bf = *(const f16x8*)&Ms[nt * 16 + col][c0 + quad * 8];
                const _Float16 cs = cfv[nt][kt];
                #pragma unroll
                for (int e = 0; e < 8; ++e) bf[e] *= cs;
                acc[nt] = __builtin_amdgcn_mfma_f32_16x16x32_f16(af[ch], bf, acc[nt], 0, 0, 0);
            }
        }
    }

    // ---- epilogue: out[b][o][u][v]
    #pragma unroll
    for (int nt = 0; nt < 8; ++nt) {
        const int v = nt * 16 + col;
        #pragma unroll
        for (int r = 0; r < 4; ++r) {
            const int o = wv * 16 + quad * 4 + r;
            out[(((size_t)b * 64 + o) * 128 + u) * 128 + v] = acc[nt][r] * SCALE;
        }
    }
}

// ----------------------------------------------------------------- launch ----
extern "C" void kernel_launch(void* const* d_in, const int* in_sizes, int n_in,
                              void* d_out, int out_size, void* d_ws, size_t ws_size,
                              hipStream_t stream)
{
    const float* x = (const float*)d_in[0];   // fp32 [8,64,128,128]
    const float* w = (const float*)d_in[1];   // fp32 [64,64,3,3]
    char* ws = (char*)d_ws;
    // byte layout:
    //   Tf  f16 @ 0          (36,864 B)     [144][128]
    //   cfT f16 @ 36,864     (2,048 B)      [128][8]
    //   X   f16 @ 65,536     (17,842,176 B) [512 x 132 x 132]
    //   hgT f16 @ 17,907,712 (6,291,456 B)  [128][6][64][64]
    // total ~24.2 MB
    _Float16* Tf  = (_Float16*)(ws);
    _Float16* cfT = (_Float16*)(ws + 36864);
    _Float16* X   = (_Float16*)(ws + 65536);
    _Float16* hgT = (_Float16*)(ws + 17907712);

    build_tf16<<<dim3(144), dim3(128), 0, stream>>>(Tf);
    build_cf<<<dim3(1), dim3(128), 0, stream>>>(cfT);

    // fused DHT2: x -> X (Tf + Y1 live in LDS)
    dht2_fused<<<dim3(512), dim3(256), 0, stream>>>(x, Tf, X);

    // per-u weight transform
    build_hgT<<<dim3(128), dim3(256), 0, stream>>>(w, hgT);

    // combine as MFMA GEMM -> fp32 out
    combine_mfma<<<dim3(128, 8), dim3(256), 0, stream>>>(
        X, hgT, cfT, (float*)d_out);
}